// Round 1
// baseline (132.002 us; speedup 1.0000x reference)
//
#include <hip/hip_runtime.h>

// Problem constants (from reference)
#define NSTARS 2048
#define BATCH  256
#define PF     28
#define NGE    512
#define GF     32
#define OPD2   65536   // 256*256
#define KTOT   (PF + GF)  // 60
#define TM     16      // batches per block in main kernel (16 -> 4 blocks/CU)
// main kernel: 256 threads * float4 = 1024 ij per block

typedef float f32x4 __attribute__((ext_vector_type(4)));

// ---------------------------------------------------------------------------
// Kernel 1: index search + W = [interm_poly | interm_graph] (k-major layout)
// Wt[k*BATCH + b], k in [0,60)
// ---------------------------------------------------------------------------
__global__ __launch_bounds__(256) void prep_kernel(
    const float* __restrict__ positions,  const float* __restrict__ obs_pos,
    const float* __restrict__ poly_dic,   const float* __restrict__ graph_dic,
    const float* __restrict__ alpha_poly, const float* __restrict__ alpha_graph,
    float* __restrict__ Wt)
{
    const int b = blockIdx.x;   // batch row
    const int t = threadIdx.x;  // 256 threads

    const float p0 = positions[2 * b];
    const float p1 = positions[2 * b + 1];

    // Faithful to argmax(eq.reshape(B,-1))//2 : first star n (row-major over
    // (n, coord)) where EITHER coordinate matches; all-false -> 0.
    int cand = 0x7fffffff;
    #pragma unroll
    for (int i = 0; i < NSTARS / 256; ++i) {
        const int n = t + i * 256;
        const float o0 = obs_pos[2 * n];
        const float o1 = obs_pos[2 * n + 1];
        if (o0 == p0 || o1 == p1) cand = min(cand, n);
    }
    __shared__ int smin[256];
    smin[t] = cand;
    __syncthreads();
    for (int s = 128; s > 0; s >>= 1) {
        if (t < s) smin[t] = min(smin[t], smin[t + s]);
        __syncthreads();
    }
    int idx = smin[0];
    if (idx == 0x7fffffff) idx = 0;  // argmax of all-False returns 0

    // interm_poly[j] = sum_p poly_dic[idx,p] * alpha_poly[p,j]
    if (t < PF) {
        float acc = 0.f;
        #pragma unroll
        for (int p = 0; p < PF; ++p)
            acc += poly_dic[idx * PF + p] * alpha_poly[p * PF + t];
        Wt[t * BATCH + b] = acc;
    }

    // interm_graph[g] = sum_e graph_dic[idx,e] * alpha_graph[e,g]
    // 8 partials of 64 elements each, reduced in LDS.
    __shared__ float psum[8][GF];
    {
        const int g = t & 31;
        const int r = t >> 5;
        float acc = 0.f;
        const int e0 = r * (NGE / 8);
        for (int e = e0; e < e0 + NGE / 8; ++e)
            acc += graph_dic[idx * NGE + e] * alpha_graph[e * GF + g];
        psum[r][g] = acc;
    }
    __syncthreads();
    if (t < GF) {
        float acc = 0.f;
        #pragma unroll
        for (int r = 0; r < 8; ++r) acc += psum[r][t];
        Wt[(PF + t) * BATCH + b] = acc;
    }
}

// ---------------------------------------------------------------------------
// Kernel 2: out[b, ij] = sum_k Wt[k, b] * S[k, ij]
// Tile: TM=16 batches x 1024 ij per block (256 thr x float4).
// grid (64, 16) = 1024 blocks = 4 blocks/CU -> 4 waves/SIMD (was 2).
// Wt addresses are block-uniform -> scalar loads; inner loop = pure v_fmac.
// Stores are nontemporal: out is write-once, keep S resident in per-XCD L2.
// ---------------------------------------------------------------------------
__global__ __launch_bounds__(256) void main_kernel(
    const float* __restrict__ S_poly, const float* __restrict__ S_graph,
    const float* __restrict__ Wt, float* __restrict__ out)
{
    const int t  = threadIdx.x;
    const int ij = blockIdx.x * 1024 + t * 4;
    const int b0 = blockIdx.y * TM;

    f32x4 acc[TM];
    #pragma unroll
    for (int b = 0; b < TM; ++b) acc[b] = (f32x4)(0.f);

    const float* __restrict__ wp = Wt + b0;

    #pragma unroll 4
    for (int k = 0; k < PF; ++k) {
        const f32x4 s = *reinterpret_cast<const f32x4*>(
            S_poly + (size_t)k * OPD2 + ij);
        #pragma unroll
        for (int b = 0; b < TM; ++b) {
            const float w = wp[k * BATCH + b];
            acc[b].x = fmaf(w, s.x, acc[b].x);
            acc[b].y = fmaf(w, s.y, acc[b].y);
            acc[b].z = fmaf(w, s.z, acc[b].z);
            acc[b].w = fmaf(w, s.w, acc[b].w);
        }
    }
    #pragma unroll 4
    for (int k = 0; k < GF; ++k) {
        const f32x4 s = *reinterpret_cast<const f32x4*>(
            S_graph + (size_t)k * OPD2 + ij);
        #pragma unroll
        for (int b = 0; b < TM; ++b) {
            const float w = wp[(PF + k) * BATCH + b];
            acc[b].x = fmaf(w, s.x, acc[b].x);
            acc[b].y = fmaf(w, s.y, acc[b].y);
            acc[b].z = fmaf(w, s.z, acc[b].z);
            acc[b].w = fmaf(w, s.w, acc[b].w);
        }
    }

    #pragma unroll
    for (int b = 0; b < TM; ++b) {
        __builtin_nontemporal_store(
            acc[b],
            reinterpret_cast<f32x4*>(out + (size_t)(b0 + b) * OPD2 + ij));
    }
}

// ---------------------------------------------------------------------------
extern "C" void kernel_launch(void* const* d_in, const int* in_sizes, int n_in,
                              void* d_out, int out_size, void* d_ws, size_t ws_size,
                              hipStream_t stream) {
    const float* positions   = (const float*)d_in[0];  // (256, 2)
    const float* obs_pos     = (const float*)d_in[1];  // (2048, 2)
    const float* poly_dic    = (const float*)d_in[2];  // (2048, 28)
    const float* graph_dic   = (const float*)d_in[3];  // (2048, 512)
    const float* alpha_poly  = (const float*)d_in[4];  // (28, 28)
    const float* alpha_graph = (const float*)d_in[5];  // (512, 32)
    const float* S_poly      = (const float*)d_in[6];  // (28, 256, 256)
    const float* S_graph     = (const float*)d_in[7];  // (32, 256, 256)
    float* out = (float*)d_out;                        // (256, 256, 256)

    float* Wt = (float*)d_ws;  // KTOT * BATCH floats = 60 KB

    prep_kernel<<<BATCH, 256, 0, stream>>>(positions, obs_pos, poly_dic,
                                           graph_dic, alpha_poly, alpha_graph,
                                           Wt);

    dim3 grid(OPD2 / 1024, BATCH / TM);  // 64 x 16 = 1024 blocks
    main_kernel<<<grid, 256, 0, stream>>>(S_poly, S_graph, Wt, out);
}

// Round 2
// 130.956 us; speedup vs baseline: 1.0080x; 1.0080x over previous
//
#include <hip/hip_runtime.h>

// Problem constants (from reference)
#define NSTARS 2048
#define BATCH  256
#define PF     28
#define NGE    512
#define GF     32
#define OPD2   65536   // 256*256
#define KTOT   (PF + GF)  // 60
#define TM     16      // batches per block in main kernel
// main kernel: 256 threads * float4 = 1024 ij per block

typedef float f32x4 __attribute__((ext_vector_type(4)));

// ---------------------------------------------------------------------------
// Kernel 1: index search + W = [interm_poly | interm_graph] (k-major layout)
// Wt[k*BATCH + b], k in [0,60)
// ---------------------------------------------------------------------------
__global__ __launch_bounds__(256) void prep_kernel(
    const float* __restrict__ positions,  const float* __restrict__ obs_pos,
    const float* __restrict__ poly_dic,   const float* __restrict__ graph_dic,
    const float* __restrict__ alpha_poly, const float* __restrict__ alpha_graph,
    float* __restrict__ Wt)
{
    const int b = blockIdx.x;   // batch row
    const int t = threadIdx.x;  // 256 threads

    const float p0 = positions[2 * b];
    const float p1 = positions[2 * b + 1];

    // Faithful to argmax(eq.reshape(B,-1))//2 : first star n (row-major over
    // (n, coord)) where EITHER coordinate matches; all-false -> 0.
    int cand = 0x7fffffff;
    #pragma unroll
    for (int i = 0; i < NSTARS / 256; ++i) {
        const int n = t + i * 256;
        const float o0 = obs_pos[2 * n];
        const float o1 = obs_pos[2 * n + 1];
        if (o0 == p0 || o1 == p1) cand = min(cand, n);
    }
    __shared__ int smin[256];
    smin[t] = cand;
    __syncthreads();
    for (int s = 128; s > 0; s >>= 1) {
        if (t < s) smin[t] = min(smin[t], smin[t + s]);
        __syncthreads();
    }
    int idx = smin[0];
    if (idx == 0x7fffffff) idx = 0;  // argmax of all-False returns 0

    // interm_poly[j] = sum_p poly_dic[idx,p] * alpha_poly[p,j]
    if (t < PF) {
        float acc = 0.f;
        #pragma unroll
        for (int p = 0; p < PF; ++p)
            acc += poly_dic[idx * PF + p] * alpha_poly[p * PF + t];
        Wt[t * BATCH + b] = acc;
    }

    // interm_graph[g] = sum_e graph_dic[idx,e] * alpha_graph[e,g]
    // 8 partials of 64 elements each, reduced in LDS.
    __shared__ float psum[8][GF];
    {
        const int g = t & 31;
        const int r = t >> 5;
        float acc = 0.f;
        const int e0 = r * (NGE / 8);
        for (int e = e0; e < e0 + NGE / 8; ++e)
            acc += graph_dic[idx * NGE + e] * alpha_graph[e * GF + g];
        psum[r][g] = acc;
    }
    __syncthreads();
    if (t < GF) {
        float acc = 0.f;
        #pragma unroll
        for (int r = 0; r < 8; ++r) acc += psum[r][t];
        Wt[(PF + t) * BATCH + b] = acc;
    }
}

// ---------------------------------------------------------------------------
// Kernel 2: out[b, ij] = sum_k Wt[k, b] * S[k, ij]
// Tile: TM=16 batches x 1024 ij per block (256 thr x float4).
// 1D grid of 1024 blocks, XCD-swizzled: block id -> xcd = id&7 owns x-slices
// [xcd*8, xcd*8+8). Each XCD's S working set = 8 x 240 KB = 1.92 MB < 4 MB L2,
// and all 16 y-sharers of a slice are co-resident on that XCD -> S-reads are
// L2 hits instead of L3 (~200 vs ~600+ cyc). Stores are nontemporal (write-
// once) so the out-stream doesn't evict S from L2.
// ---------------------------------------------------------------------------
__global__ __launch_bounds__(256) void main_kernel(
    const float* __restrict__ S_poly, const float* __restrict__ S_graph,
    const float* __restrict__ Wt, float* __restrict__ out)
{
    const int t    = threadIdx.x;
    const int id   = blockIdx.x;      // 0..1023
    const int xcd  = id & 7;
    const int slot = id >> 3;         // 0..127
    const int xb   = xcd * 8 + (slot & 7);  // 0..63  (8 x-slices per XCD)
    const int yb   = slot >> 3;             // 0..15

    const int ij = xb * 1024 + t * 4;
    const int b0 = yb * TM;

    f32x4 acc[TM];
    #pragma unroll
    for (int b = 0; b < TM; ++b) acc[b] = (f32x4)(0.f);

    const float* __restrict__ wp = Wt + b0;

    #pragma unroll 8
    for (int k = 0; k < PF; ++k) {
        const f32x4 s = *reinterpret_cast<const f32x4*>(
            S_poly + (size_t)k * OPD2 + ij);
        #pragma unroll
        for (int b = 0; b < TM; ++b) {
            const float w = wp[k * BATCH + b];
            acc[b].x = fmaf(w, s.x, acc[b].x);
            acc[b].y = fmaf(w, s.y, acc[b].y);
            acc[b].z = fmaf(w, s.z, acc[b].z);
            acc[b].w = fmaf(w, s.w, acc[b].w);
        }
    }
    #pragma unroll 8
    for (int k = 0; k < GF; ++k) {
        const f32x4 s = *reinterpret_cast<const f32x4*>(
            S_graph + (size_t)k * OPD2 + ij);
        #pragma unroll
        for (int b = 0; b < TM; ++b) {
            const float w = wp[(PF + k) * BATCH + b];
            acc[b].x = fmaf(w, s.x, acc[b].x);
            acc[b].y = fmaf(w, s.y, acc[b].y);
            acc[b].z = fmaf(w, s.z, acc[b].z);
            acc[b].w = fmaf(w, s.w, acc[b].w);
        }
    }

    #pragma unroll
    for (int b = 0; b < TM; ++b) {
        __builtin_nontemporal_store(
            acc[b],
            reinterpret_cast<f32x4*>(out + (size_t)(b0 + b) * OPD2 + ij));
    }
}

// ---------------------------------------------------------------------------
extern "C" void kernel_launch(void* const* d_in, const int* in_sizes, int n_in,
                              void* d_out, int out_size, void* d_ws, size_t ws_size,
                              hipStream_t stream) {
    const float* positions   = (const float*)d_in[0];  // (256, 2)
    const float* obs_pos     = (const float*)d_in[1];  // (2048, 2)
    const float* poly_dic    = (const float*)d_in[2];  // (2048, 28)
    const float* graph_dic   = (const float*)d_in[3];  // (2048, 512)
    const float* alpha_poly  = (const float*)d_in[4];  // (28, 28)
    const float* alpha_graph = (const float*)d_in[5];  // (512, 32)
    const float* S_poly      = (const float*)d_in[6];  // (28, 256, 256)
    const float* S_graph     = (const float*)d_in[7];  // (32, 256, 256)
    float* out = (float*)d_out;                        // (256, 256, 256)

    float* Wt = (float*)d_ws;  // KTOT * BATCH floats = 60 KB

    prep_kernel<<<BATCH, 256, 0, stream>>>(positions, obs_pos, poly_dic,
                                           graph_dic, alpha_poly, alpha_graph,
                                           Wt);

    main_kernel<<<1024, 256, 0, stream>>>(S_poly, S_graph, Wt, out);
}

// Round 3
// 125.987 us; speedup vs baseline: 1.0477x; 1.0394x over previous
//
#include <hip/hip_runtime.h>

// Problem constants (from reference)
#define NSTARS 2048
#define BATCH  256
#define PF     28
#define NGE    512
#define GF     32
#define OPD2   65536   // 256*256
#define KTOT   (PF + GF)  // 60
#define TM     16      // batches per block in main kernel
#define KB     4       // k-slices per LDS tile
#define NT     (KTOT / KB)  // 15 tiles: tiles 0..6 = S_poly (28 k), 7..14 = S_graph (32 k)

typedef float f32x4 __attribute__((ext_vector_type(4)));

// ---------------------------------------------------------------------------
// Kernel 1: index search + W = [interm_poly | interm_graph] (k-major layout)
// Wt[k*BATCH + b], k in [0,60)
// ---------------------------------------------------------------------------
__global__ __launch_bounds__(256) void prep_kernel(
    const float* __restrict__ positions,  const float* __restrict__ obs_pos,
    const float* __restrict__ poly_dic,   const float* __restrict__ graph_dic,
    const float* __restrict__ alpha_poly, const float* __restrict__ alpha_graph,
    float* __restrict__ Wt)
{
    const int b = blockIdx.x;   // batch row
    const int t = threadIdx.x;  // 256 threads

    const float p0 = positions[2 * b];
    const float p1 = positions[2 * b + 1];

    // Faithful to argmax(eq.reshape(B,-1))//2 : first star n (row-major over
    // (n, coord)) where EITHER coordinate matches; all-false -> 0.
    int cand = 0x7fffffff;
    #pragma unroll
    for (int i = 0; i < NSTARS / 256; ++i) {
        const int n = t + i * 256;
        const float o0 = obs_pos[2 * n];
        const float o1 = obs_pos[2 * n + 1];
        if (o0 == p0 || o1 == p1) cand = min(cand, n);
    }
    __shared__ int smin[256];
    smin[t] = cand;
    __syncthreads();
    for (int s = 128; s > 0; s >>= 1) {
        if (t < s) smin[t] = min(smin[t], smin[t + s]);
        __syncthreads();
    }
    int idx = smin[0];
    if (idx == 0x7fffffff) idx = 0;  // argmax of all-False returns 0

    // interm_poly[j] = sum_p poly_dic[idx,p] * alpha_poly[p,j]
    if (t < PF) {
        float acc = 0.f;
        #pragma unroll
        for (int p = 0; p < PF; ++p)
            acc += poly_dic[idx * PF + p] * alpha_poly[p * PF + t];
        Wt[t * BATCH + b] = acc;
    }

    // interm_graph[g] = sum_e graph_dic[idx,e] * alpha_graph[e,g]
    // 8 partials of 64 elements each, reduced in LDS.
    __shared__ float psum[8][GF];
    {
        const int g = t & 31;
        const int r = t >> 5;
        float acc = 0.f;
        const int e0 = r * (NGE / 8);
        for (int e = e0; e < e0 + NGE / 8; ++e)
            acc += graph_dic[idx * NGE + e] * alpha_graph[e * GF + g];
        psum[r][g] = acc;
    }
    __syncthreads();
    if (t < GF) {
        float acc = 0.f;
        #pragma unroll
        for (int r = 0; r < 8; ++r) acc += psum[r][t];
        Wt[(PF + t) * BATCH + b] = acc;
    }
}

// ---------------------------------------------------------------------------
// Kernel 2: out[b, ij] = sum_k Wt[k, b] * S[k, ij]
// TM=16 batches x 1024 ij per block (256 thr x float4), 1024 blocks,
// XCD-swizzled (each XCD owns 8 x-slices -> 1.92 MB S working set in its L2).
//
// S is staged global->LDS with explicit global_load_lds (width 16, linear
// wave-uniform dest + lane*16), double-buffered in tiles of KB=4 k-slices:
//   prologue: stage(tile0); vmcnt(0); barrier
//   loop:     stage(tile T+1) ; compute(tile T) ; vmcnt(0); barrier
// Prefetch latency hides under the 4*64 FMA issue of the current tile; the
// compiler cannot build this pipeline from plain loads (R1/R2 evidence:
// VGPR=60, VALUBusy=27% -> serialized load->wait->FMA).
// W reads are block-uniform -> scalar s_load (scalar cache, off the VALU/LDS
// critical path). Stores nontemporal (write-once).
// ---------------------------------------------------------------------------
__global__ __launch_bounds__(256) void main_kernel(
    const float* __restrict__ S_poly, const float* __restrict__ S_graph,
    const float* __restrict__ Wt, float* __restrict__ out)
{
    __shared__ float sbuf[2][KB][1024];   // 32 KB

    const int t    = threadIdx.x;
    const int id   = blockIdx.x;      // 0..1023
    const int xcd  = id & 7;
    const int slot = id >> 3;         // 0..127
    const int xb   = xcd * 8 + (slot & 7);  // 0..63  (8 x-slices per XCD)
    const int yb   = slot >> 3;             // 0..15

    const int ij = xb * 1024 + t * 4;
    const int b0 = yb * TM;

    const float* __restrict__ wp = Wt + b0;

    f32x4 acc[TM];
    #pragma unroll
    for (int b = 0; b < TM; ++b) acc[b] = (f32x4)(0.f);

    // Per-wave LDS dest base: wave-uniform, lane l lands at +l*16 bytes.
    const int wbase = (t >> 6) << 8;  // wave * 256 floats

    // stage tile T into buffer d: KB global_load_lds of 16B per thread
    auto stage = [&](int T, int d) {
        const int kb = T * KB;
        const float* base = (T < PF / KB)
            ? (S_poly  + (size_t)kb * OPD2)
            : (S_graph + (size_t)(kb - PF) * OPD2);
        const float* src = base + xb * 1024 + t * 4;  // per-lane 16B
        #pragma unroll
        for (int kk = 0; kk < KB; ++kk) {
            __builtin_amdgcn_global_load_lds(
                (const __attribute__((address_space(1))) uint32_t*)(src + (size_t)kk * OPD2),
                (__attribute__((address_space(3))) uint32_t*)&sbuf[d][kk][wbase],
                16, 0, 0);
        }
    };

    // prologue
    stage(0, 0);
    asm volatile("s_waitcnt vmcnt(0)" ::: "memory");
    __syncthreads();

    int cur = 0;
    for (int T = 0; T < NT; ++T) {
        if (T + 1 < NT) stage(T + 1, cur ^ 1);   // issue next-tile prefetch first

        const int kb = T * KB;
        #pragma unroll
        for (int kk = 0; kk < KB; ++kk) {
            const f32x4 s = *reinterpret_cast<const f32x4*>(&sbuf[cur][kk][t * 4]);
            #pragma unroll
            for (int b = 0; b < TM; ++b) {
                const float w = wp[(kb + kk) * BATCH + b];  // uniform -> s_load
                acc[b].x = fmaf(w, s.x, acc[b].x);
                acc[b].y = fmaf(w, s.y, acc[b].y);
                acc[b].z = fmaf(w, s.z, acc[b].z);
                acc[b].w = fmaf(w, s.w, acc[b].w);
            }
        }

        asm volatile("s_waitcnt vmcnt(0)" ::: "memory");  // prefetch landed
        __syncthreads();                                   // all waves done with sbuf[cur]
        cur ^= 1;
    }

    #pragma unroll
    for (int b = 0; b < TM; ++b) {
        __builtin_nontemporal_store(
            acc[b],
            reinterpret_cast<f32x4*>(out + (size_t)(b0 + b) * OPD2 + ij));
    }
}

// ---------------------------------------------------------------------------
extern "C" void kernel_launch(void* const* d_in, const int* in_sizes, int n_in,
                              void* d_out, int out_size, void* d_ws, size_t ws_size,
                              hipStream_t stream) {
    const float* positions   = (const float*)d_in[0];  // (256, 2)
    const float* obs_pos     = (const float*)d_in[1];  // (2048, 2)
    const float* poly_dic    = (const float*)d_in[2];  // (2048, 28)
    const float* graph_dic   = (const float*)d_in[3];  // (2048, 512)
    const float* alpha_poly  = (const float*)d_in[4];  // (28, 28)
    const float* alpha_graph = (const float*)d_in[5];  // (512, 32)
    const float* S_poly      = (const float*)d_in[6];  // (28, 256, 256)
    const float* S_graph     = (const float*)d_in[7];  // (32, 256, 256)
    float* out = (float*)d_out;                        // (256, 256, 256)

    float* Wt = (float*)d_ws;  // KTOT * BATCH floats = 60 KB

    prep_kernel<<<BATCH, 256, 0, stream>>>(positions, obs_pos, poly_dic,
                                           graph_dic, alpha_poly, alpha_graph,
                                           Wt);

    main_kernel<<<1024, 256, 0, stream>>>(S_poly, S_graph, Wt, out);
}